// Round 2
// baseline (696.098 us; speedup 1.0000x reference)
//
#include <hip/hip_runtime.h>

#define N_H   5000
#define N_O   15000
#define N_TOT 20000
#define DD    1024
#define E_HH  20000
#define E_OO  40000
#define E_HO  40000
#define E_TOT 100000

typedef unsigned short u16;
typedef unsigned int u32;
typedef __attribute__((ext_vector_type(8))) short short8;
typedef __attribute__((ext_vector_type(4))) float f32x4;
typedef const __attribute__((address_space(1))) u32 gas_u32;
typedef __attribute__((address_space(3))) u32 las_u32;

__device__ __forceinline__ float bf2f(u16 u) {
    union { unsigned int i; float f; } v; v.i = ((unsigned int)u) << 16; return v.f;
}
__device__ __forceinline__ u16 f2bf(float f) {
    union { float f; unsigned int i; } v; v.f = f;
    unsigned int u = v.i;
    return (u16)((u + 0x7FFFu + ((u >> 16) & 1u)) >> 16);
}

// ---------------- fp32 -> bf16 cast (8 elems/thread) ----------------------------
__global__ void cast_bf(const float* __restrict__ in, u16* __restrict__ out) {
    size_t i = ((size_t)blockIdx.x * 256 + threadIdx.x) * 8;
    float4 a = *(const float4*)(in + i);
    float4 b = *(const float4*)(in + i + 4);
    u16 o[8] = {f2bf(a.x), f2bf(a.y), f2bf(a.z), f2bf(a.w),
                f2bf(b.x), f2bf(b.y), f2bf(b.z), f2bf(b.w)};
    *(uint4*)(out + i) = *(const uint4*)o;
}

// ------- W fp32 [2048,1024] -> bf16 Wt[n][k]: top half (k<1024) to dstT, bottom to dstB
__global__ void transpose_w(const float* __restrict__ W, u16* __restrict__ dstT,
                            u16* __restrict__ dstB, int ld) {
    __shared__ float tile[32][33];
    int half = blockIdx.z;
    int bk = blockIdx.x, bn = blockIdx.y;
    int tx = threadIdx.x & 31, ty = threadIdx.x >> 5;   // ty 0..7
#pragma unroll
    for (int yy = 0; yy < 4; yy++) {
        int k = half * 1024 + bk * 32 + ty + yy * 8;
        int n = bn * 32 + tx;
        tile[ty + yy * 8][tx] = W[(size_t)k * 1024 + n];
    }
    __syncthreads();
    u16* dst = half ? dstB : dstT;
#pragma unroll
    for (int yy = 0; yy < 4; yy++) {
        int n = bn * 32 + ty + yy * 8;
        int k = bk * 32 + tx;
        dst[(size_t)n * ld + k] = f2bf(tile[tx][ty + yy * 8]);
    }
}

// ---------------- 128x128 GEMM (kept for node-apply-h: small M tail) ------------
__launch_bounds__(256)
__global__ void gemm_bt(const u16* __restrict__ A0, const u16* __restrict__ A1,
                        const u16* __restrict__ Bt, int ldb,
                        const float* __restrict__ bias,
                        void* __restrict__ Cp, int ldc, int M, int Kt,
                        int relu, int c_fp32, int nbn) {
    __shared__ u16 lA[128][64];
    __shared__ u16 lB[128][64];
    int bid = blockIdx.x;
    int bm = bid / nbn, bn = bid % nbn;
    int t = threadIdx.x;
    int wave = t >> 6, lane = t & 63;
    int wr = wave >> 1, wc = wave & 1;   // 2x2 wave grid, 64x64 each
    int lm = lane & 15, q = lane >> 4;
    f32x4 acc[4][4] = {};
    int srow = lane >> 3;                       // 0..7 within chunk
    int scol = ((lane & 7) ^ srow) * 8;         // swizzled source chunk

    for (int k0 = 0; k0 < Kt; k0 += 64) {
        const u16* Asrc = (k0 < 1024) ? A0 : A1;
        int kk = k0 & 1023;
#pragma unroll
        for (int it = 0; it < 4; it++) {
            int chunk = wave * 4 + it;           // 0..15
            int row = chunk * 8 + srow;          // tile row this lane feeds
            int gr = bm * 128 + row; if (gr >= M) gr = M - 1;
            const u16* ga = Asrc + (size_t)gr * 1024 + kk + scol;
            __builtin_amdgcn_global_load_lds((gas_u32*)ga, (las_u32*)&lA[chunk * 8][0], 16, 0, 0);
            const u16* gb = Bt + (size_t)(bn * 128 + row) * ldb + k0 + scol;
            __builtin_amdgcn_global_load_lds((gas_u32*)gb, (las_u32*)&lB[chunk * 8][0], 16, 0, 0);
        }
        __syncthreads();
#pragma unroll
        for (int ks = 0; ks < 64; ks += 32) {
            short8 af[4], bfr[4];
            int pc = (((ks >> 3) + q) ^ (lm & 7)) * 8;   // swizzled physical col
#pragma unroll
            for (int i = 0; i < 4; i++)
                af[i] = *(const short8*)&lA[wr * 64 + i * 16 + lm][pc];
#pragma unroll
            for (int j = 0; j < 4; j++)
                bfr[j] = *(const short8*)&lB[wc * 64 + j * 16 + lm][pc];
#pragma unroll
            for (int i = 0; i < 4; i++)
#pragma unroll
                for (int j = 0; j < 4; j++)
                    acc[i][j] = __builtin_amdgcn_mfma_f32_16x16x32_bf16(af[i], bfr[j], acc[i][j], 0, 0, 0);
        }
        __syncthreads();
    }
#pragma unroll
    for (int j = 0; j < 4; j++) {
        int col = bn * 128 + wc * 64 + j * 16 + lm;
        float bv = bias ? bias[col] : 0.0f;
#pragma unroll
        for (int i = 0; i < 4; i++) {
            int row0 = bm * 128 + wr * 64 + i * 16 + q * 4;
#pragma unroll
            for (int r = 0; r < 4; r++) {
                int row = row0 + r;
                if (row < M) {
                    float v = acc[i][j][r] + bv;
                    if (relu) v = fmaxf(v, 0.0f);
                    if (c_fp32) ((float*)Cp)[(size_t)row * ldc + col] = v;
                    else        ((u16*)Cp)[(size_t)row * ldc + col] = f2bf(v);
                }
            }
        }
    }
}

// ---------------- 256x256 8-phase GEMM (m201 schedule, K-half staging) ----------
// BK=64 split in 2 khalves of 32; LDS [2 buf][2 kh][256][32] per matrix = 128 KiB.
// Per phase: {ds_reads (4 or 8 b128) ; stage 1 half (2 gload_lds) ; [vmcnt(6) @P4/P8]
//             ; s_barrier ; lgkmcnt(0) ; setprio(1) ; 16 MFMA ; setprio(0) ; s_barrier}
// Stage slots (iter i, tiles t0=2i buf0, t1=2i+1 buf1):
//   P1: buf1.A.kh1 <- t1   P2: buf0.B.kh0 <- t2   P3: buf0.A.kh0 <- t2
//   P4: buf0.B.kh1 <- t2   P5: buf0.A.kh1 <- t2   P6: buf1.B.kh0 <- t3
//   P7: buf1.A.kh0 <- t3   P8: buf1.B.kh1 <- t3        (t2=2i+2, t3=2i+3, clamped)
// WAR: each slot is staged exactly one phase after the half's last reader.
// RAW: vmcnt(6) @P4 guarantees <=P1 landed (covers P5-P8 reads); @P8 guarantees
//      <=P5 landed (covers next-iter P1-P4 reads). Barrier after vmcnt publishes.
// Bank swizzle (64B rows): phys 16B-chunk = logical ^ ((row>>1)&3); consecutive
// 8 lanes cover all 8 slots of a 128B span -> <=2 lanes/bank (free). Source is
// pre-swizzled: schunk = (t&3) ^ ((t>>3)&3) (both-sides-or-neither, rule 21).
#define BAR   __builtin_amdgcn_s_barrier()
#define LGKM0 asm volatile("s_waitcnt lgkmcnt(0)" ::: "memory")
#define VM6   asm volatile("s_waitcnt vmcnt(6)" ::: "memory")
#define LOADA(B, KH, MH) \
    _Pragma("unroll") \
    for (int i_ = 0; i_ < 4; i_++) \
        af[i_] = *(const short8*)&lA[B][KH][wr * 128 + (MH) * 64 + i_ * 16 + lm][fc];
#define LOADB(B, KH) \
    _Pragma("unroll") \
    for (int j_ = 0; j_ < 4; j_++) \
        bfr[j_] = *(const short8*)&lB[B][KH][wc * 64 + j_ * 16 + lm][fc];
#define MFMA16(MH) \
    __builtin_amdgcn_s_setprio(1); \
    _Pragma("unroll") \
    for (int i_ = 0; i_ < 4; i_++) \
        _Pragma("unroll") \
        for (int j_ = 0; j_ < 4; j_++) \
            acc[(MH) * 4 + i_][j_] = __builtin_amdgcn_mfma_f32_16x16x32_bf16(af[i_], bfr[j_], acc[(MH) * 4 + i_][j_], 0, 0, 0); \
    __builtin_amdgcn_s_setprio(0);

__launch_bounds__(512, 2)
__global__ void gemm256(const u16* __restrict__ A0, const u16* __restrict__ A1,
                        const u16* __restrict__ Bt, int ldb,
                        const float* __restrict__ bias,
                        void* __restrict__ Cp, int ldc, int M, int Kt,
                        int relu, int c_fp32, int nbn) {
    __shared__ u16 lA[2][2][256][32];
    __shared__ u16 lB[2][2][256][32];
    int nwg = gridDim.x;
    int bid = blockIdx.x;
    int cq = nwg >> 3, cr = nwg & 7;
    int xcd = bid & 7, ord = bid >> 3;
    int swz = (xcd < cr ? xcd * (cq + 1) : cr * (cq + 1) + (xcd - cr) * cq) + ord;
    int bm = swz / nbn, bn = swz % nbn;
    int t = threadIdx.x;
    int wave = t >> 6, lane = t & 63;
    int wr = wave >> 2, wc = wave & 3;          // 2M x 4N waves, 128x64 out each
    int lm = lane & 15, qv = lane >> 4;
    int srow = t >> 2;                          // staging row (r*128 + srow)
    int schunk = (t & 3) ^ ((t >> 3) & 3);      // pre-swizzled source k-chunk
    int fc = (qv ^ ((lm >> 1) & 3)) * 8;        // swizzled frag elem offset
    int NT = Kt >> 6;                           // 64-k tiles (must be even, >=2)
    f32x4 acc[8][4] = {};

    auto stage_a = [&](int ts, int b, int kh) {
        int k0 = ts * 64 + kh * 32;
        const u16* Asrc = (k0 < 1024) ? A0 : A1;
        int kk = (k0 & 1023) + schunk * 8;
#pragma unroll
        for (int r = 0; r < 2; r++) {
            int gr = bm * 256 + r * 128 + srow; if (gr >= M) gr = M - 1;
            __builtin_amdgcn_global_load_lds(
                (gas_u32*)(Asrc + (size_t)gr * 1024 + kk),
                (las_u32*)((char*)&lA[b][kh][0][0] + r * 8192 + wave * 1024), 16, 0, 0);
        }
    };
    auto stage_b = [&](int ts, int b, int kh) {
        int kk = ts * 64 + kh * 32 + schunk * 8;
#pragma unroll
        for (int r = 0; r < 2; r++) {
            int gr = bn * 256 + r * 128 + srow;
            __builtin_amdgcn_global_load_lds(
                (gas_u32*)(Bt + (size_t)gr * ldb + kk),
                (las_u32*)((char*)&lB[b][kh][0][0] + r * 8192 + wave * 1024), 16, 0, 0);
        }
    };

    // prologue: t0 fully (4 halves) + t1 {A0,B0,B1}; t1.A1 comes from P1 of it2=0
    stage_a(0, 0, 0); stage_b(0, 0, 0); stage_a(0, 0, 1); stage_b(0, 0, 1);
    stage_a(1, 1, 0); stage_b(1, 1, 0); stage_b(1, 1, 1);
    VM6;          // t0 all landed (3 newest halves may fly)
    BAR;

    int NI = NT >> 1;
    short8 af[4], bfr[4];
    for (int it2 = 0; it2 < NI; ++it2) {
        int tb = 2 * it2;
        int t2c = (tb + 2 < NT) ? tb + 2 : NT - 1;
        int t3c = (tb + 3 < NT) ? tb + 3 : NT - 1;
        // P1: buf0 kh0 mh0
        LOADA(0, 0, 0) LOADB(0, 0)
        stage_a(tb + 1, 1, 1);
        BAR; LGKM0; MFMA16(0) BAR;
        // P2: buf0 kh0 mh1 (bfr reused)
        LOADA(0, 0, 1)
        stage_b(t2c, 0, 0);
        BAR; LGKM0; MFMA16(1) BAR;
        // P3: buf0 kh1 mh0
        LOADA(0, 1, 0) LOADB(0, 1)
        stage_a(t2c, 0, 0);
        BAR; LGKM0; MFMA16(0) BAR;
        // P4: buf0 kh1 mh1
        LOADA(0, 1, 1)
        stage_b(t2c, 0, 1);
        VM6;
        BAR; LGKM0; MFMA16(1) BAR;
        // P5: buf1 kh0 mh0
        LOADA(1, 0, 0) LOADB(1, 0)
        stage_a(t2c, 0, 1);
        BAR; LGKM0; MFMA16(0) BAR;
        // P6: buf1 kh0 mh1
        LOADA(1, 0, 1)
        stage_b(t3c, 1, 0);
        BAR; LGKM0; MFMA16(1) BAR;
        // P7: buf1 kh1 mh0
        LOADA(1, 1, 0) LOADB(1, 1)
        stage_a(t3c, 1, 0);
        BAR; LGKM0; MFMA16(0) BAR;
        // P8: buf1 kh1 mh1
        LOADA(1, 1, 1)
        stage_b(t3c, 1, 1);
        VM6;
        BAR; LGKM0; MFMA16(1) BAR;
    }
    asm volatile("s_waitcnt vmcnt(0)" ::: "memory");  // drain before LDS freed

    // D layout per 16x16 tile: row = qv*4+r, col = lm
#pragma unroll
    for (int j = 0; j < 4; j++) {
        int col = bn * 256 + wc * 64 + j * 16 + lm;
        float bv = bias ? bias[col] : 0.0f;
#pragma unroll
        for (int i = 0; i < 8; i++) {
            int row0 = bm * 256 + wr * 128 + i * 16 + qv * 4;
#pragma unroll
            for (int r = 0; r < 4; r++) {
                int row = row0 + r;
                if (row < M) {
                    float v = acc[i][j][r] + bv;
                    if (relu) v = fmaxf(v, 0.0f);
                    if (c_fp32) ((float*)Cp)[(size_t)row * ldc + col] = v;
                    else        ((u16*)Cp)[(size_t)row * ldc + col] = f2bf(v);
                }
            }
        }
    }
}

// ---------------- concat edge index arrays --------------------------------------
__global__ void cat_edges(const int* __restrict__ shh, const int* __restrict__ dhh,
                          const int* __restrict__ soo, const int* __restrict__ doo,
                          const int* __restrict__ sho, const int* __restrict__ dho,
                          int* __restrict__ src_all, int* __restrict__ dst_all) {
    int e = blockIdx.x * 256 + threadIdx.x;
    if (e >= E_TOT) return;
    int s, d;
    if (e < E_HH)              { s = shh[e];               d = dhh[e]; }
    else if (e < E_HH + E_OO)  { s = soo[e - E_HH];        d = doo[e - E_HH]; }
    else                       { s = sho[e - E_HH - E_OO]; d = dho[e - E_HH - E_OO]; }
    src_all[e] = s; dst_all[e] = d;
}

// --------- per-edge logit: a = ReLU(u[s]+v[d]+b) . W_att + b_att ----------------
__global__ void edge_att(const u16* __restrict__ proj_h, const u16* __restrict__ proj_o,
                         const float* __restrict__ b_hh, const float* __restrict__ b_oo,
                         const float* __restrict__ b_ho, const float* __restrict__ W_att,
                         const float* __restrict__ b_att,
                         const int* __restrict__ src_all, const int* __restrict__ dst_all,
                         float* __restrict__ a_out) {
    int e = blockIdx.x * 4 + (threadIdx.x >> 6);
    int lane = threadIdx.x & 63;
    if (e >= E_TOT) return;
    int s = src_all[e], d = dst_all[e];
    const u16 *u, *v; const float* b;
    if (e < E_HH) {
        u = proj_h + (size_t)s * 3072;
        v = proj_h + (size_t)d * 3072 + 1024;
        b = b_hh;
    } else if (e < E_HH + E_OO) {
        u = proj_o + (size_t)(s - N_H) * 3072;
        v = proj_o + (size_t)(d - N_H) * 3072 + 1024;
        b = b_oo;
    } else {
        u = proj_h + (size_t)s * 3072 + 2048;
        v = proj_o + (size_t)(d - N_H) * 3072 + 2048;
        b = b_ho;
    }
    float acc = 0.f;
#pragma unroll
    for (int c = 0; c < 2; c++) {
        int off = lane * 16 + c * 8;
        uint4 uu = *(const uint4*)(u + off);
        uint4 vv = *(const uint4*)(v + off);
        float4 b0 = *(const float4*)(b + off);
        float4 b1 = *(const float4*)(b + off + 4);
        float4 w0 = *(const float4*)(W_att + off);
        float4 w1 = *(const float4*)(W_att + off + 4);
        const u16* pu = (const u16*)&uu;
        const u16* pv = (const u16*)&vv;
        float bb[8] = {b0.x, b0.y, b0.z, b0.w, b1.x, b1.y, b1.z, b1.w};
        float ww[8] = {w0.x, w0.y, w0.z, w0.w, w1.x, w1.y, w1.z, w1.w};
#pragma unroll
        for (int i = 0; i < 8; i++) {
            float tv = bf2f(pu[i]) + bf2f(pv[i]) + bb[i];
            tv = fmaxf(tv, 0.f);
            acc += tv * ww[i];
        }
    }
#pragma unroll
    for (int o = 32; o > 0; o >>= 1) acc += __shfl_down(acc, o);
    if (lane == 0) a_out[e] = acc + b_att[0];
}

// ---------------- CSR build -----------------------------------------------------
__global__ void deg_count(const int* __restrict__ dst_all, int* __restrict__ deg) {
    int e = blockIdx.x * 256 + threadIdx.x;
    if (e < E_TOT) atomicAdd(&deg[dst_all[e]], 1);
}

__global__ void scan_deg(const int* __restrict__ deg, int* __restrict__ indptr) {
    __shared__ int sums[1024];
    int t = threadIdx.x;
    const int CH = 20;                       // 1024*20 >= 20000
    int beg = t * CH, end = beg + CH;
    if (end > N_TOT) end = N_TOT;
    if (beg > N_TOT) beg = N_TOT;
    int s = 0;
    for (int i = beg; i < end; i++) s += deg[i];
    sums[t] = s;
    __syncthreads();
    for (int off = 1; off < 1024; off <<= 1) {
        int v = sums[t];
        int add = (t >= off) ? sums[t - off] : 0;
        __syncthreads();
        sums[t] = v + add;
        __syncthreads();
    }
    int run = (t == 0) ? 0 : sums[t - 1];
    for (int i = beg; i < end; i++) { indptr[i] = run; run += deg[i]; }
    if (t == 1023) indptr[N_TOT] = sums[1023];
}

__global__ void fill_csr(const int* __restrict__ dst_all, const int* __restrict__ indptr,
                         int* __restrict__ cursor, int* __restrict__ edge_ids) {
    int e = blockIdx.x * 256 + threadIdx.x;
    if (e < E_TOT) {
        int d = dst_all[e];
        int pos = atomicAdd(&cursor[d], 1);
        edge_ids[indptr[d] + pos] = e;
    }
}

// ---------------- per-dst softmax + weighted aggregation of nf_bf[src] ----------
#define MAXDEG 1024
__global__ void soft_z(const float* __restrict__ a, const int* __restrict__ indptr,
                       const int* __restrict__ edge_ids, const int* __restrict__ src_all,
                       const u16* __restrict__ nf, u16* __restrict__ z) {
    __shared__ float s_a[MAXDEG];
    __shared__ int   s_src[MAXDEG];
    __shared__ float s_inv;
    int node = blockIdx.x;
    int t = threadIdx.x;
    int beg = indptr[node], end = indptr[node + 1];
    int deg = end - beg; if (deg > MAXDEG) deg = MAXDEG;
    if (t < 64) {
        float m = -1e30f;
        for (int i = t; i < deg; i += 64) {
            int eid = edge_ids[beg + i];
            float av = a[eid];
            s_a[i] = av;
            s_src[i] = src_all[eid];
            if (av > m) m = av;
        }
        for (int o = 32; o > 0; o >>= 1) m = fmaxf(m, __shfl_down(m, o));
        m = __shfl(m, 0);
        float ssum = 0.f;
        for (int i = t; i < deg; i += 64) {
            float ex = __expf(s_a[i] - m);
            s_a[i] = ex;
            ssum += ex;
        }
        for (int o = 32; o > 0; o >>= 1) ssum += __shfl_down(ssum, o);
        if (t == 0) s_inv = (ssum > 0.f) ? 1.0f / ssum : 0.f;
    }
    __syncthreads();
    float a0 = 0.f, a1 = 0.f, a2 = 0.f, a3 = 0.f;
    int base = t * 4;
    float inv = s_inv;
    for (int i = 0; i < deg; i++) {
        float al = s_a[i] * inv;
        const u16* row = nf + (size_t)s_src[i] * DD + base;
        uint2 p = *(const uint2*)row;
        const u16* pp = (const u16*)&p;
        a0 += al * bf2f(pp[0]); a1 += al * bf2f(pp[1]);
        a2 += al * bf2f(pp[2]); a3 += al * bf2f(pp[3]);
    }
    uint2 ov;
    u16* po = (u16*)&ov;
    po[0] = f2bf(a0); po[1] = f2bf(a1); po[2] = f2bf(a2); po[3] = f2bf(a3);
    *(uint2*)(z + (size_t)node * DD + base) = ov;
}

// ---------------- launch --------------------------------------------------------
extern "C" void kernel_launch(void* const* d_in, const int* in_sizes, int n_in,
                              void* d_out, int out_size, void* d_ws, size_t ws_size,
                              hipStream_t stream) {
    const float* nf   = (const float*)d_in[0];
    const int* shh    = (const int*)d_in[1];
    const int* dhh    = (const int*)d_in[2];
    const int* soo    = (const int*)d_in[3];
    const int* doo    = (const int*)d_in[4];
    const int* sho    = (const int*)d_in[5];
    const int* dho    = (const int*)d_in[6];
    const float* W_hh = (const float*)d_in[7];
    const float* b_hh = (const float*)d_in[8];
    const float* W_oo = (const float*)d_in[9];
    const float* b_oo = (const float*)d_in[10];
    const float* W_ho = (const float*)d_in[11];
    const float* b_ho = (const float*)d_in[12];
    const float* W_att= (const float*)d_in[13];
    const float* b_att= (const float*)d_in[14];
    const float* W_hn = (const float*)d_in[15];
    const float* b_hn = (const float*)d_in[16];
    const float* W_on = (const float*)d_in[17];
    const float* b_on = (const float*)d_in[18];
    float* out = (float*)d_out;

    char* ws = (char*)d_ws;
    size_t off = 0;
    auto alloc = [&](size_t bytes) -> char* {
        char* p = ws + off;
        off += (bytes + 255) & ~(size_t)255;
        return p;
    };
    u16* nf_bf = (u16*)alloc((size_t)N_TOT * DD * 2);          // 41.9 MB
    u16* Bt_h  = (u16*)alloc((size_t)3072 * 1024 * 2);         // 6.3 MB
    u16* Bt_o  = (u16*)alloc((size_t)3072 * 1024 * 2);
    u16* Bt_hn = (u16*)alloc((size_t)1024 * 2048 * 2);         // 4.2 MB
    u16* Bt_on = (u16*)alloc((size_t)1024 * 2048 * 2);
    u16* proj_h = (u16*)alloc((size_t)N_H * 3072 * 2);         // 30.7 MB
    u16* proj_o = (u16*)alloc((size_t)N_O * 3072 * 2);         // 92.2 MB
    u16* z_bf   = proj_h;   // aliases proj (dead after edge_att); 41.9 <= 122.9 MB
    float* a_log  = (float*)alloc(E_TOT * 4);
    int* src_all  = (int*)alloc(E_TOT * 4);
    int* dst_all  = (int*)alloc(E_TOT * 4);
    int* deg      = (int*)alloc(2 * N_TOT * 4);
    int* cursor   = deg + N_TOT;
    int* indptr   = (int*)alloc((N_TOT + 1) * 4);
    int* edge_ids = (int*)alloc(E_TOT * 4);
    (void)ws_size; (void)in_sizes; (void)n_in; (void)out_size;

    // casts + transposes
    cast_bf<<<(N_TOT * DD) / (256 * 8), 256, 0, stream>>>(nf, nf_bf);
    dim3 tgrid(32, 32, 2);
    transpose_w<<<tgrid, 256, 0, stream>>>(W_hh, Bt_h,                       Bt_h + (size_t)1024 * 1024, 1024);
    transpose_w<<<tgrid, 256, 0, stream>>>(W_oo, Bt_o,                       Bt_o + (size_t)1024 * 1024, 1024);
    transpose_w<<<tgrid, 256, 0, stream>>>(W_ho, Bt_h + (size_t)2048 * 1024, Bt_o + (size_t)2048 * 1024, 1024);
    transpose_w<<<tgrid, 256, 0, stream>>>(W_hn, Bt_hn,                      Bt_hn + 1024, 2048);
    transpose_w<<<tgrid, 256, 0, stream>>>(W_on, Bt_on,                      Bt_on + 1024, 2048);

    cat_edges<<<(E_TOT + 255) / 256, 256, 0, stream>>>(shh, dhh, soo, doo, sho, dho, src_all, dst_all);
    hipMemsetAsync(deg, 0, 2 * N_TOT * 4, stream);

    const u16* nf_bf_o = nf_bf + (size_t)N_H * DD;
    // projections: proj_h [5000,3072], proj_o [15000,3072] — 8-phase 256^2 GEMM
    int nbm256_h = (N_H + 255) / 256, nbm256_o = (N_O + 255) / 256;
    gemm256<<<nbm256_h * 12, 512, 0, stream>>>(nf_bf,   nullptr, Bt_h, 1024, nullptr, proj_h, 3072, N_H, 1024, 0, 0, 12);
    gemm256<<<nbm256_o * 12, 512, 0, stream>>>(nf_bf_o, nullptr, Bt_o, 1024, nullptr, proj_o, 3072, N_O, 1024, 0, 0, 12);

    edge_att<<<(E_TOT + 3) / 4, 256, 0, stream>>>(proj_h, proj_o, b_hh, b_oo, b_ho,
                                                  W_att, b_att, src_all, dst_all, a_log);

    deg_count<<<(E_TOT + 255) / 256, 256, 0, stream>>>(dst_all, deg);
    scan_deg<<<1, 1024, 0, stream>>>(deg, indptr);
    fill_csr<<<(E_TOT + 255) / 256, 256, 0, stream>>>(dst_all, indptr, cursor, edge_ids);

    soft_z<<<N_TOT, 256, 0, stream>>>(a_log, indptr, edge_ids, src_all, nf_bf, z_bf);

    // node apply: out = relu([nf | z] @ W) fp32
    int nbm_h = (N_H + 127) / 128;
    gemm_bt<<<nbm_h * 8, 256, 0, stream>>>(nf_bf, z_bf, Bt_hn, 2048, b_hn, out, 1024, N_H, 2048, 1, 1, 8);
    gemm256<<<nbm256_o * 4, 512, 0, stream>>>(nf_bf_o, z_bf + (size_t)N_H * DD, Bt_on, 2048, b_on, out + (size_t)N_H * DD, 1024, N_O, 2048, 1, 1, 4);
}

// Round 3
// 610.763 us; speedup vs baseline: 1.1397x; 1.1397x over previous
//
#include <hip/hip_runtime.h>

#define N_H   5000
#define N_O   15000
#define N_TOT 20000
#define DD    1024
#define E_HH  20000
#define E_OO  40000
#define E_HO  40000
#define E_TOT 100000

typedef unsigned short u16;
typedef unsigned int u32;
typedef __attribute__((ext_vector_type(8))) short short8;
typedef __attribute__((ext_vector_type(4))) float f32x4;
typedef const __attribute__((address_space(1))) u32 gas_u32;
typedef __attribute__((address_space(3))) u32 las_u32;

__device__ __forceinline__ float bf2f(u16 u) {
    union { unsigned int i; float f; } v; v.i = ((unsigned int)u) << 16; return v.f;
}
__device__ __forceinline__ u16 f2bf(float f) {
    union { float f; unsigned int i; } v; v.f = f;
    unsigned int u = v.i;
    return (u16)((u + 0x7FFFu + ((u >> 16) & 1u)) >> 16);
}

// ---------------- fp32 -> bf16 cast (8 elems/thread) ----------------------------
__global__ void cast_bf(const float* __restrict__ in, u16* __restrict__ out) {
    size_t i = ((size_t)blockIdx.x * 256 + threadIdx.x) * 8;
    float4 a = *(const float4*)(in + i);
    float4 b = *(const float4*)(in + i + 4);
    u16 o[8] = {f2bf(a.x), f2bf(a.y), f2bf(a.z), f2bf(a.w),
                f2bf(b.x), f2bf(b.y), f2bf(b.z), f2bf(b.w)};
    *(uint4*)(out + i) = *(const uint4*)o;
}

// ------- W fp32 [2048,1024] -> bf16 Wt[n][k]: top half (k<1024) to dstT, bottom to dstB
__global__ void transpose_w(const float* __restrict__ W, u16* __restrict__ dstT,
                            u16* __restrict__ dstB, int ld) {
    __shared__ float tile[32][33];
    int half = blockIdx.z;
    int bk = blockIdx.x, bn = blockIdx.y;
    int tx = threadIdx.x & 31, ty = threadIdx.x >> 5;   // ty 0..7
#pragma unroll
    for (int yy = 0; yy < 4; yy++) {
        int k = half * 1024 + bk * 32 + ty + yy * 8;
        int n = bn * 32 + tx;
        tile[ty + yy * 8][tx] = W[(size_t)k * 1024 + n];
    }
    __syncthreads();
    u16* dst = half ? dstB : dstT;
#pragma unroll
    for (int yy = 0; yy < 4; yy++) {
        int n = bn * 32 + ty + yy * 8;
        int k = bk * 32 + tx;
        dst[(size_t)n * ld + k] = f2bf(tile[tx][ty + yy * 8]);
    }
}

// ---------------- merged proj GEMM: 128x128 tile, compile-time proj constants ---
// C[M,3072] = A[M,1024] @ Bt^T, bf16 out, no bias/relu. Blocks [0,960) = h part,
// [960, 960+2832) = o part. LDS-bounce epilogue: acc -> LDS (exactly 32 KiB) ->
// 256B-contiguous dwordx4 stores (kills the 2x 32B-sector write amplification
// measured as WRITE_SIZE 187MB vs 92MB ideal).
#define PROJ_NBM_H 40           // ceil(5000/128)
#define PROJ_NBM_O 118          // ceil(15000/128)
#define PROJ_NBN   24           // 3072/128
__launch_bounds__(256)
__global__ void gemm_proj(const u16* __restrict__ Ah, const u16* __restrict__ Ao,
                          const u16* __restrict__ Bth, const u16* __restrict__ Bto,
                          u16* __restrict__ Ch, u16* __restrict__ Co) {
    __shared__ u16 smem[2][128][64];          // staging A | B; reused by epilogue
    int bid = blockIdx.x;
    const u16* A; const u16* Bt; u16* C; int M;
    if (bid < PROJ_NBM_H * PROJ_NBN) { A = Ah; Bt = Bth; C = Ch; M = N_H; }
    else { bid -= PROJ_NBM_H * PROJ_NBN; A = Ao; Bt = Bto; C = Co; M = N_O; }
    int bm = bid / PROJ_NBN, bn = bid % PROJ_NBN;
    int t = threadIdx.x;
    int wave = t >> 6, lane = t & 63;
    int wr = wave >> 1, wc = wave & 1;        // 2x2 wave grid, 64x64 each
    int lm = lane & 15, q = lane >> 4;
    f32x4 acc[4][4] = {};
    int srow = lane >> 3;                     // 0..7 within chunk
    int scol = ((lane & 7) ^ srow) * 8;       // pre-swizzled source chunk

    for (int k0 = 0; k0 < 1024; k0 += 64) {
#pragma unroll
        for (int it = 0; it < 4; it++) {
            int chunk = wave * 4 + it;        // 0..15
            int row = chunk * 8 + srow;
            int gr = bm * 128 + row; if (gr >= M) gr = M - 1;
            __builtin_amdgcn_global_load_lds((gas_u32*)(A + (size_t)gr * 1024 + k0 + scol),
                                             (las_u32*)&smem[0][chunk * 8][0], 16, 0, 0);
            __builtin_amdgcn_global_load_lds((gas_u32*)(Bt + (size_t)(bn * 128 + row) * 1024 + k0 + scol),
                                             (las_u32*)&smem[1][chunk * 8][0], 16, 0, 0);
        }
        __syncthreads();
#pragma unroll
        for (int ks = 0; ks < 64; ks += 32) {
            short8 af[4], bfr[4];
            int pc = (((ks >> 3) + q) ^ (lm & 7)) * 8;
#pragma unroll
            for (int i = 0; i < 4; i++)
                af[i] = *(const short8*)&smem[0][wr * 64 + i * 16 + lm][pc];
#pragma unroll
            for (int j = 0; j < 4; j++)
                bfr[j] = *(const short8*)&smem[1][wc * 64 + j * 16 + lm][pc];
#pragma unroll
            for (int i = 0; i < 4; i++)
#pragma unroll
                for (int j = 0; j < 4; j++)
                    acc[i][j] = __builtin_amdgcn_mfma_f32_16x16x32_bf16(af[i], bfr[j], acc[i][j], 0, 0, 0);
        }
        __syncthreads();   // also guards epilogue LDS reuse (all reads of smem done)
    }
    // acc -> LDS as the full 128x128 bf16 C-tile
    u16* sc = &smem[0][0][0];
#pragma unroll
    for (int i = 0; i < 4; i++)
#pragma unroll
        for (int j = 0; j < 4; j++)
#pragma unroll
            for (int r = 0; r < 4; r++)
                sc[(wr * 64 + i * 16 + q * 4 + r) * 128 + (wc * 64 + j * 16 + lm)] =
                    f2bf(acc[i][j][r]);
    __syncthreads();
    // 256B-contiguous stores: 16 threads cover one 128-col row
#pragma unroll
    for (int it = 0; it < 8; it++) {
        int flat = it * 256 + t;              // 0..2047
        int r = flat >> 4, cs = (flat & 15) * 8;
        int grow = bm * 128 + r;
        if (grow < M)
            *(uint4*)&C[(size_t)grow * 3072 + bn * 128 + cs] = *(const uint4*)&sc[r * 128 + cs];
    }
}

// ---------------- generic 128x128 GEMM (node-apply-h) ---------------------------
__launch_bounds__(256)
__global__ void gemm_bt(const u16* __restrict__ A0, const u16* __restrict__ A1,
                        const u16* __restrict__ Bt, int ldb,
                        const float* __restrict__ bias,
                        void* __restrict__ Cp, int ldc, int M, int Kt,
                        int relu, int c_fp32, int nbn) {
    __shared__ u16 lA[128][64];
    __shared__ u16 lB[128][64];
    int bid = blockIdx.x;
    int bm = bid / nbn, bn = bid % nbn;
    int t = threadIdx.x;
    int wave = t >> 6, lane = t & 63;
    int wr = wave >> 1, wc = wave & 1;   // 2x2 wave grid, 64x64 each
    int lm = lane & 15, q = lane >> 4;
    f32x4 acc[4][4] = {};
    int srow = lane >> 3;                       // 0..7 within chunk
    int scol = ((lane & 7) ^ srow) * 8;         // swizzled source chunk

    for (int k0 = 0; k0 < Kt; k0 += 64) {
        const u16* Asrc = (k0 < 1024) ? A0 : A1;
        int kk = k0 & 1023;
#pragma unroll
        for (int it = 0; it < 4; it++) {
            int chunk = wave * 4 + it;           // 0..15
            int row = chunk * 8 + srow;          // tile row this lane feeds
            int gr = bm * 128 + row; if (gr >= M) gr = M - 1;
            const u16* ga = Asrc + (size_t)gr * 1024 + kk + scol;
            __builtin_amdgcn_global_load_lds((gas_u32*)ga, (las_u32*)&lA[chunk * 8][0], 16, 0, 0);
            const u16* gb = Bt + (size_t)(bn * 128 + row) * ldb + k0 + scol;
            __builtin_amdgcn_global_load_lds((gas_u32*)gb, (las_u32*)&lB[chunk * 8][0], 16, 0, 0);
        }
        __syncthreads();
#pragma unroll
        for (int ks = 0; ks < 64; ks += 32) {
            short8 af[4], bfr[4];
            int pc = (((ks >> 3) + q) ^ (lm & 7)) * 8;   // swizzled physical col
#pragma unroll
            for (int i = 0; i < 4; i++)
                af[i] = *(const short8*)&lA[wr * 64 + i * 16 + lm][pc];
#pragma unroll
            for (int j = 0; j < 4; j++)
                bfr[j] = *(const short8*)&lB[wc * 64 + j * 16 + lm][pc];
#pragma unroll
            for (int i = 0; i < 4; i++)
#pragma unroll
                for (int j = 0; j < 4; j++)
                    acc[i][j] = __builtin_amdgcn_mfma_f32_16x16x32_bf16(af[i], bfr[j], acc[i][j], 0, 0, 0);
        }
        __syncthreads();
    }
#pragma unroll
    for (int j = 0; j < 4; j++) {
        int col = bn * 128 + wc * 64 + j * 16 + lm;
        float bv = bias ? bias[col] : 0.0f;
#pragma unroll
        for (int i = 0; i < 4; i++) {
            int row0 = bm * 128 + wr * 64 + i * 16 + q * 4;
#pragma unroll
            for (int r = 0; r < 4; r++) {
                int row = row0 + r;
                if (row < M) {
                    float v = acc[i][j][r] + bv;
                    if (relu) v = fmaxf(v, 0.0f);
                    if (c_fp32) ((float*)Cp)[(size_t)row * ldc + col] = v;
                    else        ((u16*)Cp)[(size_t)row * ldc + col] = f2bf(v);
                }
            }
        }
    }
}

// ---------------- 256x256 8-phase GEMM (node-apply-o) ---------------------------
#define BAR   __builtin_amdgcn_s_barrier()
#define LGKM0 asm volatile("s_waitcnt lgkmcnt(0)" ::: "memory")
#define VM6   asm volatile("s_waitcnt vmcnt(6)" ::: "memory")
#define LOADA(B, KH, MH) \
    _Pragma("unroll") \
    for (int i_ = 0; i_ < 4; i_++) \
        af[i_] = *(const short8*)&lA[B][KH][wr * 128 + (MH) * 64 + i_ * 16 + lm][fc];
#define LOADB(B, KH) \
    _Pragma("unroll") \
    for (int j_ = 0; j_ < 4; j_++) \
        bfr[j_] = *(const short8*)&lB[B][KH][wc * 64 + j_ * 16 + lm][fc];
#define MFMA16(MH) \
    __builtin_amdgcn_s_setprio(1); \
    _Pragma("unroll") \
    for (int i_ = 0; i_ < 4; i_++) \
        _Pragma("unroll") \
        for (int j_ = 0; j_ < 4; j_++) \
            acc[(MH) * 4 + i_][j_] = __builtin_amdgcn_mfma_f32_16x16x32_bf16(af[i_], bfr[j_], acc[(MH) * 4 + i_][j_], 0, 0, 0); \
    __builtin_amdgcn_s_setprio(0);

__launch_bounds__(512, 2)
__global__ void gemm256(const u16* __restrict__ A0, const u16* __restrict__ A1,
                        const u16* __restrict__ Bt, int ldb,
                        const float* __restrict__ bias,
                        void* __restrict__ Cp, int ldc, int M, int Kt,
                        int relu, int c_fp32, int nbn) {
    __shared__ u16 lA[2][2][256][32];
    __shared__ u16 lB[2][2][256][32];
    int nwg = gridDim.x;
    int bid = blockIdx.x;
    int cq = nwg >> 3, cr = nwg & 7;
    int xcd = bid & 7, ord = bid >> 3;
    int swz = (xcd < cr ? xcd * (cq + 1) : cr * (cq + 1) + (xcd - cr) * cq) + ord;
    int bm = swz / nbn, bn = swz % nbn;
    int t = threadIdx.x;
    int wave = t >> 6, lane = t & 63;
    int wr = wave >> 2, wc = wave & 3;          // 2M x 4N waves, 128x64 out each
    int lm = lane & 15, qv = lane >> 4;
    int srow = t >> 2;                          // staging row (r*128 + srow)
    int schunk = (t & 3) ^ ((t >> 3) & 3);      // pre-swizzled source k-chunk
    int fc = (qv ^ ((lm >> 1) & 3)) * 8;        // swizzled frag elem offset
    int NT = Kt >> 6;                           // 64-k tiles (even, >=4)
    f32x4 acc[8][4] = {};

    auto stage_a = [&](int ts, int b, int kh) {
        int k0 = ts * 64 + kh * 32;
        const u16* Asrc = (k0 < 1024) ? A0 : A1;
        int kk = (k0 & 1023) + schunk * 8;
#pragma unroll
        for (int r = 0; r < 2; r++) {
            int gr = bm * 256 + r * 128 + srow; if (gr >= M) gr = M - 1;
            __builtin_amdgcn_global_load_lds(
                (gas_u32*)(Asrc + (size_t)gr * 1024 + kk),
                (las_u32*)((char*)&lA[b][kh][0][0] + r * 8192 + wave * 1024), 16, 0, 0);
        }
    };
    auto stage_b = [&](int ts, int b, int kh) {
        int kk = ts * 64 + kh * 32 + schunk * 8;
#pragma unroll
        for (int r = 0; r < 2; r++) {
            int gr = bn * 256 + r * 128 + srow;
            __builtin_amdgcn_global_load_lds(
                (gas_u32*)(Bt + (size_t)gr * ldb + kk),
                (las_u32*)((char*)&lB[b][kh][0][0] + r * 8192 + wave * 1024), 16, 0, 0);
        }
    };

    stage_a(0, 0, 0); stage_b(0, 0, 0); stage_a(0, 0, 1); stage_b(0, 0, 1);
    stage_a(1, 1, 0); stage_b(1, 1, 0); stage_b(1, 1, 1);
    VM6;
    BAR;

    int NI = NT >> 1;
    short8 af[4], bfr[4];
    for (int it2 = 0; it2 < NI; ++it2) {
        int tb = 2 * it2;
        int t2c = (tb + 2 < NT) ? tb + 2 : NT - 1;
        int t3c = (tb + 3 < NT) ? tb + 3 : NT - 1;
        LOADA(0, 0, 0) LOADB(0, 0)
        stage_a(tb + 1, 1, 1);
        BAR; LGKM0; MFMA16(0) BAR;
        LOADA(0, 0, 1)
        stage_b(t2c, 0, 0);
        BAR; LGKM0; MFMA16(1) BAR;
        LOADA(0, 1, 0) LOADB(0, 1)
        stage_a(t2c, 0, 0);
        BAR; LGKM0; MFMA16(0) BAR;
        LOADA(0, 1, 1)
        stage_b(t2c, 0, 1);
        VM6;
        BAR; LGKM0; MFMA16(1) BAR;
        LOADA(1, 0, 0) LOADB(1, 0)
        stage_a(t2c, 0, 1);
        BAR; LGKM0; MFMA16(0) BAR;
        LOADA(1, 0, 1)
        stage_b(t3c, 1, 0);
        BAR; LGKM0; MFMA16(1) BAR;
        LOADA(1, 1, 0) LOADB(1, 1)
        stage_a(t3c, 1, 0);
        BAR; LGKM0; MFMA16(0) BAR;
        LOADA(1, 1, 1)
        stage_b(t3c, 1, 1);
        VM6;
        BAR; LGKM0; MFMA16(1) BAR;
    }
    asm volatile("s_waitcnt vmcnt(0)" ::: "memory");

#pragma unroll
    for (int j = 0; j < 4; j++) {
        int col = bn * 256 + wc * 64 + j * 16 + lm;
        float bv = bias ? bias[col] : 0.0f;
#pragma unroll
        for (int i = 0; i < 8; i++) {
            int row0 = bm * 256 + wr * 128 + i * 16 + qv * 4;
#pragma unroll
            for (int r = 0; r < 4; r++) {
                int row = row0 + r;
                if (row < M) {
                    float v = acc[i][j][r] + bv;
                    if (relu) v = fmaxf(v, 0.0f);
                    if (c_fp32) ((float*)Cp)[(size_t)row * ldc + col] = v;
                    else        ((u16*)Cp)[(size_t)row * ldc + col] = f2bf(v);
                }
            }
        }
    }
}

// ---------------- concat edge index arrays + degree count (fused) ---------------
__global__ void cat_edges(const int* __restrict__ shh, const int* __restrict__ dhh,
                          const int* __restrict__ soo, const int* __restrict__ doo,
                          const int* __restrict__ sho, const int* __restrict__ dho,
                          int* __restrict__ src_all, int* __restrict__ dst_all,
                          int* __restrict__ deg) {
    int e = blockIdx.x * 256 + threadIdx.x;
    if (e >= E_TOT) return;
    int s, d;
    if (e < E_HH)              { s = shh[e];               d = dhh[e]; }
    else if (e < E_HH + E_OO)  { s = soo[e - E_HH];        d = doo[e - E_HH]; }
    else                       { s = sho[e - E_HH - E_OO]; d = dho[e - E_HH - E_OO]; }
    src_all[e] = s; dst_all[e] = d;
    atomicAdd(&deg[d], 1);
}

// --------- per-edge logit: a = ReLU(u[s]+v[d]+b) . W_att + b_att ----------------
__global__ void edge_att(const u16* __restrict__ proj_h, const u16* __restrict__ proj_o,
                         const float* __restrict__ b_hh, const float* __restrict__ b_oo,
                         const float* __restrict__ b_ho, const float* __restrict__ W_att,
                         const float* __restrict__ b_att,
                         const int* __restrict__ src_all, const int* __restrict__ dst_all,
                         float* __restrict__ a_out) {
    int e = blockIdx.x * 4 + (threadIdx.x >> 6);
    int lane = threadIdx.x & 63;
    if (e >= E_TOT) return;
    int s = src_all[e], d = dst_all[e];
    const u16 *u, *v; const float* b;
    if (e < E_HH) {
        u = proj_h + (size_t)s * 3072;
        v = proj_h + (size_t)d * 3072 + 1024;
        b = b_hh;
    } else if (e < E_HH + E_OO) {
        u = proj_o + (size_t)(s - N_H) * 3072;
        v = proj_o + (size_t)(d - N_H) * 3072 + 1024;
        b = b_oo;
    } else {
        u = proj_h + (size_t)s * 3072 + 2048;
        v = proj_o + (size_t)(d - N_H) * 3072 + 2048;
        b = b_ho;
    }
    float acc = 0.f;
#pragma unroll
    for (int c = 0; c < 2; c++) {
        int off = lane * 16 + c * 8;
        uint4 uu = *(const uint4*)(u + off);
        uint4 vv = *(const uint4*)(v + off);
        float4 b0 = *(const float4*)(b + off);
        float4 b1 = *(const float4*)(b + off + 4);
        float4 w0 = *(const float4*)(W_att + off);
        float4 w1 = *(const float4*)(W_att + off + 4);
        const u16* pu = (const u16*)&uu;
        const u16* pv = (const u16*)&vv;
        float bb[8] = {b0.x, b0.y, b0.z, b0.w, b1.x, b1.y, b1.z, b1.w};
        float ww[8] = {w0.x, w0.y, w0.z, w0.w, w1.x, w1.y, w1.z, w1.w};
#pragma unroll
        for (int i = 0; i < 8; i++) {
            float tv = bf2f(pu[i]) + bf2f(pv[i]) + bb[i];
            tv = fmaxf(tv, 0.f);
            acc += tv * ww[i];
        }
    }
#pragma unroll
    for (int o = 32; o > 0; o >>= 1) acc += __shfl_down(acc, o);
    if (lane == 0) a_out[e] = acc + b_att[0];
}

// ---------------- CSR build -----------------------------------------------------
__global__ void scan_deg(const int* __restrict__ deg, int* __restrict__ indptr) {
    __shared__ int sums[1024];
    int t = threadIdx.x;
    const int CH = 20;                       // 1024*20 >= 20000
    int beg = t * CH, end = beg + CH;
    if (end > N_TOT) end = N_TOT;
    if (beg > N_TOT) beg = N_TOT;
    int s = 0;
    for (int i = beg; i < end; i++) s += deg[i];
    sums[t] = s;
    __syncthreads();
    for (int off = 1; off < 1024; off <<= 1) {
        int v = sums[t];
        int add = (t >= off) ? sums[t - off] : 0;
        __syncthreads();
        sums[t] = v + add;
        __syncthreads();
    }
    int run = (t == 0) ? 0 : sums[t - 1];
    for (int i = beg; i < end; i++) { indptr[i] = run; run += deg[i]; }
    if (t == 1023) indptr[N_TOT] = sums[1023];
}

__global__ void fill_csr(const int* __restrict__ dst_all, const int* __restrict__ indptr,
                         int* __restrict__ cursor, int* __restrict__ edge_ids) {
    int e = blockIdx.x * 256 + threadIdx.x;
    if (e < E_TOT) {
        int d = dst_all[e];
        int pos = atomicAdd(&cursor[d], 1);
        edge_ids[indptr[d] + pos] = e;
    }
}

// ---------------- per-dst softmax + weighted aggregation of nf_bf[src] ----------
#define MAXDEG 1024
__global__ void soft_z(const float* __restrict__ a, const int* __restrict__ indptr,
                       const int* __restrict__ edge_ids, const int* __restrict__ src_all,
                       const u16* __restrict__ nf, u16* __restrict__ z) {
    __shared__ float s_a[MAXDEG];
    __shared__ int   s_src[MAXDEG];
    __shared__ float s_inv;
    int node = blockIdx.x;
    int t = threadIdx.x;
    int beg = indptr[node], end = indptr[node + 1];
    int deg = end - beg; if (deg > MAXDEG) deg = MAXDEG;
    if (t < 64) {
        float m = -1e30f;
        for (int i = t; i < deg; i += 64) {
            int eid = edge_ids[beg + i];
            float av = a[eid];
            s_a[i] = av;
            s_src[i] = src_all[eid];
            if (av > m) m = av;
        }
        for (int o = 32; o > 0; o >>= 1) m = fmaxf(m, __shfl_down(m, o));
        m = __shfl(m, 0);
        float ssum = 0.f;
        for (int i = t; i < deg; i += 64) {
            float ex = __expf(s_a[i] - m);
            s_a[i] = ex;
            ssum += ex;
        }
        for (int o = 32; o > 0; o >>= 1) ssum += __shfl_down(ssum, o);
        if (t == 0) s_inv = (ssum > 0.f) ? 1.0f / ssum : 0.f;
    }
    __syncthreads();
    float a0 = 0.f, a1 = 0.f, a2 = 0.f, a3 = 0.f;
    int base = t * 4;
    float inv = s_inv;
    for (int i = 0; i < deg; i++) {
        float al = s_a[i] * inv;
        const u16* row = nf + (size_t)s_src[i] * DD + base;
        uint2 p = *(const uint2*)row;
        const u16* pp = (const u16*)&p;
        a0 += al * bf2f(pp[0]); a1 += al * bf2f(pp[1]);
        a2 += al * bf2f(pp[2]); a3 += al * bf2f(pp[3]);
    }
    uint2 ov;
    u16* po = (u16*)&ov;
    po[0] = f2bf(a0); po[1] = f2bf(a1); po[2] = f2bf(a2); po[3] = f2bf(a3);
    *(uint2*)(z + (size_t)node * DD + base) = ov;
}

// ---------------- launch --------------------------------------------------------
extern "C" void kernel_launch(void* const* d_in, const int* in_sizes, int n_in,
                              void* d_out, int out_size, void* d_ws, size_t ws_size,
                              hipStream_t stream) {
    const float* nf   = (const float*)d_in[0];
    const int* shh    = (const int*)d_in[1];
    const int* dhh    = (const int*)d_in[2];
    const int* soo    = (const int*)d_in[3];
    const int* doo    = (const int*)d_in[4];
    const int* sho    = (const int*)d_in[5];
    const int* dho    = (const int*)d_in[6];
    const float* W_hh = (const float*)d_in[7];
    const float* b_hh = (const float*)d_in[8];
    const float* W_oo = (const float*)d_in[9];
    const float* b_oo = (const float*)d_in[10];
    const float* W_ho = (const float*)d_in[11];
    const float* b_ho = (const float*)d_in[12];
    const float* W_att= (const float*)d_in[13];
    const float* b_att= (const float*)d_in[14];
    const float* W_hn = (const float*)d_in[15];
    const float* b_hn = (const float*)d_in[16];
    const float* W_on = (const float*)d_in[17];
    const float* b_on = (const float*)d_in[18];
    float* out = (float*)d_out;

    char* ws = (char*)d_ws;
    size_t off = 0;
    auto alloc = [&](size_t bytes) -> char* {
        char* p = ws + off;
        off += (bytes + 255) & ~(size_t)255;
        return p;
    };
    u16* nf_bf = (u16*)alloc((size_t)N_TOT * DD * 2);          // 41.9 MB
    u16* Bt_h  = (u16*)alloc((size_t)3072 * 1024 * 2);         // 6.3 MB
    u16* Bt_o  = (u16*)alloc((size_t)3072 * 1024 * 2);
    u16* Bt_hn = (u16*)alloc((size_t)1024 * 2048 * 2);         // 4.2 MB
    u16* Bt_on = (u16*)alloc((size_t)1024 * 2048 * 2);
    u16* proj_h = (u16*)alloc((size_t)N_H * 3072 * 2);         // 30.7 MB
    u16* proj_o = (u16*)alloc((size_t)N_O * 3072 * 2);         // 92.2 MB
    u16* z_bf   = proj_h;   // aliases proj (dead after edge_att)
    float* a_log  = (float*)alloc(E_TOT * 4);
    int* src_all  = (int*)alloc(E_TOT * 4);
    int* dst_all  = (int*)alloc(E_TOT * 4);
    int* deg      = (int*)alloc(2 * N_TOT * 4);
    int* cursor   = deg + N_TOT;
    int* indptr   = (int*)alloc((N_TOT + 1) * 4);
    int* edge_ids = (int*)alloc(E_TOT * 4);
    (void)ws_size; (void)in_sizes; (void)n_in; (void)out_size;

    // casts + transposes
    cast_bf<<<(N_TOT * DD) / (256 * 8), 256, 0, stream>>>(nf, nf_bf);
    dim3 tgrid(32, 32, 2);
    transpose_w<<<tgrid, 256, 0, stream>>>(W_hh, Bt_h,                       Bt_h + (size_t)1024 * 1024, 1024);
    transpose_w<<<tgrid, 256, 0, stream>>>(W_oo, Bt_o,                       Bt_o + (size_t)1024 * 1024, 1024);
    transpose_w<<<tgrid, 256, 0, stream>>>(W_ho, Bt_h + (size_t)2048 * 1024, Bt_o + (size_t)2048 * 1024, 1024);
    transpose_w<<<tgrid, 256, 0, stream>>>(W_hn, Bt_hn,                      Bt_hn + 1024, 2048);
    transpose_w<<<tgrid, 256, 0, stream>>>(W_on, Bt_on,                      Bt_on + 1024, 2048);

    hipMemsetAsync(deg, 0, 2 * N_TOT * 4, stream);
    cat_edges<<<(E_TOT + 255) / 256, 256, 0, stream>>>(shh, dhh, soo, doo, sho, dho,
                                                       src_all, dst_all, deg);

    const u16* nf_bf_o = nf_bf + (size_t)N_H * DD;
    // merged projections: blocks [0,960) h-part, [960,3792) o-part
    gemm_proj<<<(PROJ_NBM_H + PROJ_NBM_O) * PROJ_NBN, 256, 0, stream>>>(
        nf_bf, nf_bf_o, Bt_h, Bt_o, proj_h, proj_o);

    edge_att<<<(E_TOT + 3) / 4, 256, 0, stream>>>(proj_h, proj_o, b_hh, b_oo, b_ho,
                                                  W_att, b_att, src_all, dst_all, a_log);

    scan_deg<<<1, 1024, 0, stream>>>(deg, indptr);
    fill_csr<<<(E_TOT + 255) / 256, 256, 0, stream>>>(dst_all, indptr, cursor, edge_ids);

    soft_z<<<N_TOT, 256, 0, stream>>>(a_log, indptr, edge_ids, src_all, nf_bf, z_bf);

    // node apply: out = relu([nf | z] @ W) fp32
    int nbm_h = (N_H + 127) / 128;
    int nbm256_o = (N_O + 255) / 256;
    gemm_bt<<<nbm_h * 8, 256, 0, stream>>>(nf_bf, z_bf, Bt_hn, 2048, b_hn, out, 1024, N_H, 2048, 1, 1, 8);
    gemm256<<<nbm256_o * 4, 512, 0, stream>>>(nf_bf_o, z_bf + (size_t)N_H * DD, Bt_on, 2048, b_on, out + (size_t)N_H * DD, 1024, N_O, 2048, 1, 1, 4);
}